// Round 15
// baseline (160.880 us; speedup 1.0000x reference)
//
#include <hip/hip_runtime.h>
#include <math.h>

#define HN0 1373
#define BM 128
#define BN 128
#define BK 32
#define LDT 40  // GEMM LDS row stride in bf16 elems (80B = 5 x 16B units)

typedef __attribute__((ext_vector_type(8))) short short8;
typedef __attribute__((ext_vector_type(4))) float f32x4;

__device__ inline unsigned short f2bf(float f) {
  unsigned int u = __float_as_uint(f);
  unsigned int r = (u + 0x7FFFu + ((u >> 16) & 1u)) >> 16;
  return (unsigned short)r;
}
__device__ inline float bflo(unsigned int u) { return __uint_as_float(u << 16); }
__device__ inline float bfhi(unsigned int u) { return __uint_as_float(u & 0xFFFF0000u); }

__device__ inline uint4 pack8bf(float4 a, float4 b) {
  uint4 o;
  o.x = (unsigned)f2bf(a.x) | ((unsigned)f2bf(a.y) << 16);
  o.y = (unsigned)f2bf(a.z) | ((unsigned)f2bf(a.w) << 16);
  o.z = (unsigned)f2bf(b.x) | ((unsigned)f2bf(b.y) << 16);
  o.w = (unsigned)f2bf(b.z) | ((unsigned)f2bf(b.w) << 16);
  return o;
}

// ---- fused prep: W transpose | A->bf16 | node norms | deg hist --------------
__global__ __launch_bounds__(256) void prep(
    const float* __restrict__ Wp0, const float* __restrict__ Wr0,
    const float* __restrict__ Wp1, const float* __restrict__ Wr1,
    unsigned short* __restrict__ BTw,
    const float* __restrict__ A, unsigned short* __restrict__ A_bf,
    const float* __restrict__ sloc, const float* __restrict__ topo,
    unsigned short* __restrict__ slt, unsigned short* __restrict__ sltn,
    const int* __restrict__ dst, int* __restrict__ deg, int N, int E) {
  __shared__ float T[64][72];
  int b = blockIdx.x;
  int tid = threadIdx.x;
  int aBlocks = (N + 7) / 8;
  int nodeBlocks = (N + 7) / 8;
  if (b < 64) {
    int mat = b >> 4;
    int t16 = b & 15;
    int kT = (t16 & 3) * 64;
    int nT = (t16 >> 2) * 64;
    const float* W = (mat == 0) ? Wp0 : (mat == 1) ? Wr0 : (mat == 2) ? Wp1 : Wr1;
    int g = mat >> 1;
    int nbase = (mat & 1) * 256;
    int r = tid >> 2;
    int cb = (tid & 3) * 16;
    const float* srcp = W + (size_t)(kT + r) * 256 + nT + cb;
#pragma unroll
    for (int q = 0; q < 4; ++q) {
      float4 v = *reinterpret_cast<const float4*>(srcp + q * 4);
      T[cb + q * 4 + 0][r] = v.x;
      T[cb + q * 4 + 1][r] = v.y;
      T[cb + q * 4 + 2][r] = v.z;
      T[cb + q * 4 + 3][r] = v.w;
    }
    __syncthreads();
    int nl = tid >> 2;
    int kb = (tid & 3) * 16;
    unsigned int pk[8];
#pragma unroll
    for (int q = 0; q < 8; ++q) {
      unsigned short lo = f2bf(T[nl][kb + q * 2]);
      unsigned short hi = f2bf(T[nl][kb + q * 2 + 1]);
      pk[q] = (unsigned)lo | ((unsigned)hi << 16);
    }
    unsigned short* dstp = BTw + (size_t)g * 512 * 256 + (size_t)(nbase + nT + nl) * 256 + kT + kb;
    *reinterpret_cast<uint4*>(dstp) = make_uint4(pk[0], pk[1], pk[2], pk[3]);
    *reinterpret_cast<uint4*>(dstp + 8) = make_uint4(pk[4], pk[5], pk[6], pk[7]);
  } else if (b < 64 + aBlocks) {
    int row = (b - 64) * 8 + (tid >> 5);
    if (row >= N) return;
    int cb = (tid & 31) * 8;
    const float* ap = A + (size_t)row * 256 + cb;
    float4 v0 = *reinterpret_cast<const float4*>(ap);
    float4 v1 = *reinterpret_cast<const float4*>(ap + 4);
    *reinterpret_cast<uint4*>(A_bf + (size_t)row * 256 + cb) = pack8bf(v0, v1);
  } else if (b < 64 + aBlocks + nodeBlocks) {
    int node = (b - 64 - aBlocks) * 8 + (tid >> 5);
    int d = tid & 31;
    if (node >= N) return;
    float s = sloc[(size_t)node * 32 + d];
    float t = topo[(size_t)node * 32 + d];
    float ss = s * s, tt = t * t;
#pragma unroll
    for (int m = 16; m >= 1; m >>= 1) {
      ss += __shfl_xor(ss, m);
      tt += __shfl_xor(tt, m);
    }
    float is = 1.f / fmaxf(sqrtf(ss), 1e-12f);
    float it = 1.f / fmaxf(sqrtf(tt), 1e-12f);
    slt[(size_t)node * 64 + d] = f2bf(s);
    slt[(size_t)node * 64 + 32 + d] = f2bf(t);
    sltn[(size_t)node * 64 + d] = f2bf(s * is);
    sltn[(size_t)node * 64 + 32 + d] = f2bf(t * it);
  } else {
    int e = (b - 64 - aBlocks - nodeBlocks) * 256 + tid;
    if (e < E) atomicAdd(&deg[dst[e]], 1);
  }
}

// ---- K2: MFMA GEMM (bf16 A, XCD-swizzled) + decoupled CSR scan --------------
__global__ __launch_bounds__(256) void gemm_scan(
    const unsigned short* __restrict__ A_bf, const unsigned short* __restrict__ BTw,
    unsigned short* __restrict__ feat_bf, unsigned short* __restrict__ resval,
    const int* __restrict__ deg, int* __restrict__ start, int* __restrict__ bsum,
    int* __restrict__ gctr, int Gpad, int R, int N) {
  int b = blockIdx.x;
  int tid = threadIdx.x;
  if (b >= Gpad) {
    __shared__ int buf[256];
    int b2 = b - Gpad;
    int gid = b2 * 256 + tid;
    int v = (gid < N) ? deg[gid] : 0;
    buf[tid] = v;
    __syncthreads();
    for (int off = 1; off < 256; off <<= 1) {
      int t = (tid >= off) ? buf[tid - off] : 0;
      __syncthreads();
      buf[tid] += t;
      __syncthreads();
    }
    if (gid < N) start[gid] = buf[tid] - v;
    if (tid == 255) bsum[b2] = atomicAdd(gctr, buf[255]);
    return;
  }
  int r8 = b & 7;
  int c = (b >> 3) & 3;
  int bx = (b >> 5) * 8 + r8;
  if (bx >= R) return;
  int colBase = c * BN;

  __shared__ __align__(16) unsigned short As[BM * LDT];
  __shared__ __align__(16) unsigned short Bs[BN * LDT];
  int lane = tid & 63;
  int w = tid >> 6;
  int wr = w >> 1, wc = w & 1;

  int g0t = (HN0 + BM - 1) / BM;
  bool g1 = bx >= g0t;
  int rowBase = g1 ? HN0 + (bx - g0t) * BM : bx * BM;
  int rowEnd = g1 ? N : HN0;
  const unsigned short* BT = BTw + (g1 ? (size_t)512 * 256 : 0);

  int r0 = tid >> 2;
  int kp = (tid & 3) << 3;
  int ar1 = min(rowBase + r0, rowEnd - 1);
  int ar2 = min(rowBase + r0 + 64, rowEnd - 1);
  const unsigned short* aP1 = A_bf + (size_t)ar1 * 256 + kp;
  const unsigned short* aP2 = A_bf + (size_t)ar2 * 256 + kp;
  const unsigned short* bP1 = BT + (size_t)(colBase + r0) * 256 + kp;
  const unsigned short* bP2 = bP1 + (size_t)64 * 256;
  int wo1 = r0 * LDT + kp;
  int wo2 = (r0 + 64) * LDT + kp;

  int q = lane >> 4;
  int fr = lane & 15;
  int aOff = (wr * 64 + fr) * LDT + q * 8;
  int bOff = (wc * 64 + fr) * LDT + q * 8;

  f32x4 acc[4][4] = {};

  uint4 ra1 = *reinterpret_cast<const uint4*>(aP1);
  uint4 ra2 = *reinterpret_cast<const uint4*>(aP2);
  uint4 rb1 = *reinterpret_cast<const uint4*>(bP1);
  uint4 rb2 = *reinterpret_cast<const uint4*>(bP2);

  for (int t = 0; t < 8; ++t) {
    *reinterpret_cast<uint4*>(&As[wo1]) = ra1;
    *reinterpret_cast<uint4*>(&As[wo2]) = ra2;
    *reinterpret_cast<uint4*>(&Bs[wo1]) = rb1;
    *reinterpret_cast<uint4*>(&Bs[wo2]) = rb2;
    __syncthreads();
    if (t < 7) {
      int ko = (t + 1) * BK;
      ra1 = *reinterpret_cast<const uint4*>(aP1 + ko);
      ra2 = *reinterpret_cast<const uint4*>(aP2 + ko);
      rb1 = *reinterpret_cast<const uint4*>(bP1 + ko);
      rb2 = *reinterpret_cast<const uint4*>(bP2 + ko);
    }
    short8 af[4], bf4[4];
#pragma unroll
    for (int i = 0; i < 4; ++i) {
      af[i] = *reinterpret_cast<const short8*>(&As[aOff + i * 16 * LDT]);
      bf4[i] = *reinterpret_cast<const short8*>(&Bs[bOff + i * 16 * LDT]);
    }
#pragma unroll
    for (int i = 0; i < 4; ++i)
#pragma unroll
      for (int j = 0; j < 4; ++j)
        acc[i][j] = __builtin_amdgcn_mfma_f32_16x16x32_bf16(af[i], bf4[j], acc[i][j], 0, 0, 0);
    __syncthreads();
  }

  unsigned short* outp = (colBase < 256) ? feat_bf : resval;
  int cOff = colBase & 255;
#pragma unroll
  for (int i = 0; i < 4; ++i) {
    int rb = rowBase + wr * 64 + i * 16 + q * 4;
#pragma unroll
    for (int j = 0; j < 4; ++j) {
      int col = cOff + wc * 64 + j * 16 + fr;
      f32x4 v = acc[i][j];
#pragma unroll
      for (int rr = 0; rr < 4; ++rr) {
        int r = rb + rr;
        if (r < rowEnd) outp[(size_t)r * 256 + col] = f2bf(v[rr]);
      }
    }
  }
}

// ---- K3: attn_probs (blocks < nAttn, conflict-free LDS) ∪ fill_sim ----------
#define HSTR 36
__global__ __launch_bounds__(256) void attn_fill(
    const unsigned short* __restrict__ feat_bf, const float* __restrict__ W_prob,
    unsigned short* __restrict__ ft_attn, float* __restrict__ col_ss,
    const int* __restrict__ src, const int* __restrict__ dst,
    const int* __restrict__ e_feat, const float* __restrict__ etype_attn,
    const unsigned short* __restrict__ sltn,
    const int* __restrict__ start, const int* __restrict__ bsum,
    int* __restrict__ cursor, int2* __restrict__ csr,
    int nAttn, int N, int E) {
  int tid = threadIdx.x;
  if ((int)blockIdx.x >= nAttn) {
    int j = tid & 3;
    int e = ((int)blockIdx.x - nAttn) * 64 + (tid >> 2);
    if (e >= E) return;
    int s = src[e], d = dst[e];
    const unsigned short* ps = sltn + (size_t)s * 64 + j * 16;
    const unsigned short* pd = sltn + (size_t)d * 64 + j * 16;
    uint4 a0 = *reinterpret_cast<const uint4*>(ps);
    uint4 a1 = *reinterpret_cast<const uint4*>(ps + 8);
    uint4 b0 = *reinterpret_cast<const uint4*>(pd);
    uint4 b1 = *reinterpret_cast<const uint4*>(pd + 8);
    float u = bflo(a0.x) * bflo(b0.x) + bfhi(a0.x) * bfhi(b0.x) +
              bflo(a0.y) * bflo(b0.y) + bfhi(a0.y) * bfhi(b0.y) +
              bflo(a0.z) * bflo(b0.z) + bfhi(a0.z) * bfhi(b0.z) +
              bflo(a0.w) * bflo(b0.w) + bfhi(a0.w) * bfhi(b0.w) +
              bflo(a1.x) * bflo(b1.x) + bfhi(a1.x) * bfhi(b1.x) +
              bflo(a1.y) * bflo(b1.y) + bfhi(a1.y) * bfhi(b1.y) +
              bflo(a1.z) * bflo(b1.z) + bfhi(a1.z) * bfhi(b1.z) +
              bflo(a1.w) * bflo(b1.w) + bfhi(a1.w) * bfhi(b1.w);
    u *= (j < 2) ? 0.4f : 0.6f;
    u += __shfl_xor(u, 1);
    u += __shfl_xor(u, 2);
    if (j == 0) {
      float sim = fmaf(u, 0.5f, 0.5f);
      float wv = sim * etype_attn[e_feat[e]];
      int pos = start[d] + bsum[d >> 8] + atomicAdd(&cursor[d], 1);
      csr[pos] = make_int2(s, __float_as_int(wv));
    }
    return;
  }
  __shared__ float fsL[16 * 8 * HSTR];
  int h = tid >> 5, g = tid & 31;
  float wreg[32];
#pragma unroll
  for (int f = 0; f < 32; ++f) wreg[f] = W_prob[h * 1024 + f * 32 + g];
  int nodeBase = blockIdx.x * 16;
  {
    int nloc = tid >> 6;
    int cb = (tid & 63) * 4;
    int hh = cb >> 5, ff = cb & 31;
#pragma unroll
    for (int it = 0; it < 4; ++it) {
      int nl = it * 4 + nloc;
      int n = nodeBase + nl;
      float4 v = make_float4(0.f, 0.f, 0.f, 0.f);
      if (n < N) {
        uint2 p = *reinterpret_cast<const uint2*>(feat_bf + (size_t)n * 256 + cb);
        v = make_float4(bflo(p.x), bfhi(p.x), bflo(p.y), bfhi(p.y));
      }
      *reinterpret_cast<float4*>(&fsL[nl * 8 * HSTR + hh * HSTR + ff]) = v;
    }
  }
  __syncthreads();
  {
    float ssp = 0.f;
#pragma unroll
    for (int nl = 0; nl < 16; ++nl) {
      float v = fsL[nl * 8 * HSTR + h * HSTR + g];
      ssp += v * v;
    }
    atomicAdd(&col_ss[tid], ssp);
  }
  for (int i = 0; i < 16; ++i) {
    int n = nodeBase + i;
    if (n >= N) break;
    const float* frp = &fsL[i * 8 * HSTR + h * HSTR];
    float t0 = 0.f, t1 = 0.f, t2 = 0.f, t3 = 0.f;
#pragma unroll
    for (int f = 0; f < 8; ++f) {
      t0 = fmaf(frp[f * 4 + 0], wreg[f * 4 + 0], t0);
      t1 = fmaf(frp[f * 4 + 1], wreg[f * 4 + 1], t1);
      t2 = fmaf(frp[f * 4 + 2], wreg[f * 4 + 2], t2);
      t3 = fmaf(frp[f * 4 + 3], wreg[f * 4 + 3], t3);
    }
    float t = (t0 + t1) + (t2 + t3);
    float e2 = __expf(2.f * t);
    t = 1.f - 2.f * __builtin_amdgcn_rcpf(e2 + 1.f);
    float ex = __expf(t);
    float sm = ex;
#pragma unroll
    for (int s = 16; s >= 1; s >>= 1) sm += __shfl_xor(sm, s);
    ft_attn[(size_t)n * 256 + tid] = f2bf(ex * __builtin_amdgcn_rcpf(sm));
  }
}

// ---- main: 2 waves per node (even/odd edges), lean depth-3 per wave ---------
#define LOADIDX(K, V, W)                                                       \
  do {                                                                         \
    int2 c_ = csr[s0 + half + 2 * (K)];                                        \
    V = c_.x;                                                                  \
    W = __int_as_float(c_.y);                                                  \
  } while (0)

#define GATHER(V, FP, SL, TP)                                                  \
  do {                                                                         \
    FP = *reinterpret_cast<const uint2*>(feat_bf + (size_t)(V) * 256 + fb);    \
    const unsigned short* sp_ = slt + (size_t)(V) * 64 + db;                   \
    SL = *reinterpret_cast<const uint2*>(sp_);                                 \
    TP = *reinterpret_cast<const uint2*>(sp_ + 32);                            \
  } while (0)

#define CONSUME(W, FP, SL, TP)                                                 \
  do {                                                                         \
    float fs0 = bflo(FP.x), fs1 = bfhi(FP.x);                                  \
    float fs2 = bflo(FP.y), fs3 = bfhi(FP.y);                                  \
    float pa = ai4.x * fs0 + ai4.y * fs1 + ai4.z * fs2 + ai4.w * fs3;          \
    pa += __shfl_xor(pa, 1);                                                   \
    pa += __shfl_xor(pa, 2);                                                   \
    pa += __shfl_xor(pa, 4);                                                   \
    float p = __expf(pa * (W));                                                \
    l += p;                                                                    \
    accf.x = fmaf(p, fs0, accf.x); accf.y = fmaf(p, fs1, accf.y);              \
    accf.z = fmaf(p, fs2, accf.z); accf.w = fmaf(p, fs3, accf.w);              \
    accs.x = fmaf(p, bflo(SL.x), accs.x); accs.y = fmaf(p, bfhi(SL.x), accs.y);\
    accs.z = fmaf(p, bflo(SL.y), accs.z); accs.w = fmaf(p, bfhi(SL.y), accs.w);\
    acct.x = fmaf(p, bflo(TP.x), acct.x); acct.y = fmaf(p, bfhi(TP.x), acct.y);\
    acct.z = fmaf(p, bflo(TP.y), acct.z); acct.w = fmaf(p, bfhi(TP.y), acct.w);\
  } while (0)

__global__ __launch_bounds__(128) void edge_aggregate(
    const unsigned short* __restrict__ feat_bf, const unsigned short* __restrict__ resval,
    const unsigned short* __restrict__ ft_attn, const float* __restrict__ col_ss,
    const unsigned short* __restrict__ slt,
    const float* __restrict__ sloc, const float* __restrict__ topo,
    const int* __restrict__ start, const int* __restrict__ bsum,
    const int* __restrict__ deg, const int2* __restrict__ csr,
    float* __restrict__ out, int N) {
  __shared__ float comb[13][64];
  int half = threadIdx.x >> 6;
  int n = blockIdx.x;
  int lane = threadIdx.x & 63;
  int j = lane & 7;
  int fb = (lane >> 3) * 32 + j * 4;
  int db = j * 4;

  uint2 at2 = *reinterpret_cast<const uint2*>(ft_attn + (size_t)n * 256 + fb);
  float4 cs4 = *reinterpret_cast<const float4*>(col_ss + fb);
  float4 icn4 = make_float4(1.f / fmaxf(sqrtf(cs4.x), 1e-12f),
                            1.f / fmaxf(sqrtf(cs4.y), 1e-12f),
                            1.f / fmaxf(sqrtf(cs4.z), 1e-12f),
                            1.f / fmaxf(sqrtf(cs4.w), 1e-12f));
  float4 ai4 = make_float4(bflo(at2.x) * icn4.x, bfhi(at2.x) * icn4.y,
                           bflo(at2.y) * icn4.z, bfhi(at2.y) * icn4.w);
  float l = 0.f;
  float4 accf = make_float4(0.f, 0.f, 0.f, 0.f);
  float4 accs = make_float4(0.f, 0.f, 0.f, 0.f);
  float4 acct = make_float4(0.f, 0.f, 0.f, 0.f);
  int s0 = start[n] + bsum[n >> 8];
  int dg = deg[n];
  int cnt = (dg > half) ? ((dg - half + 1) >> 1) : 0;

  int vA = 0, vB = 0, vC = 0;
  float wA = 0.f, wB = 0.f, wC = 0.f;
  uint2 fpA = make_uint2(0u, 0u), fpB = make_uint2(0u, 0u), fpC = make_uint2(0u, 0u);
  uint2 slA = make_uint2(0u, 0u), slB = make_uint2(0u, 0u), slC = make_uint2(0u, 0u);
  uint2 tpA = make_uint2(0u, 0u), tpB = make_uint2(0u, 0u), tpC = make_uint2(0u, 0u);
  if (cnt > 0) { LOADIDX(0, vA, wA); GATHER(vA, fpA, slA, tpA); }
  if (cnt > 1) { LOADIDX(1, vB, wB); GATHER(vB, fpB, slB, tpB); }
  if (cnt > 2) { LOADIDX(2, vC, wC); GATHER(vC, fpC, slC, tpC); }
  int k = 0;
  for (; k + 2 < cnt; k += 3) {
    CONSUME(wA, fpA, slA, tpA);
    if (k + 3 < cnt) { LOADIDX(k + 3, vA, wA); GATHER(vA, fpA, slA, tpA); }
    CONSUME(wB, fpB, slB, tpB);
    if (k + 4 < cnt) { LOADIDX(k + 4, vB, wB); GATHER(vB, fpB, slB, tpB); }
    CONSUME(wC, fpC, slC, tpC);
    if (k + 5 < cnt) { LOADIDX(k + 5, vC, wC); GATHER(vC, fpC, slC, tpC); }
  }
  if (k < cnt) CONSUME(wA, fpA, slA, tpA);
  if (k + 1 < cnt) CONSUME(wB, fpB, slB, tpB);

  if (half == 1) {
    comb[0][lane] = l;
    comb[1][lane] = accf.x; comb[2][lane] = accf.y;
    comb[3][lane] = accf.z; comb[4][lane] = accf.w;
    comb[5][lane] = accs.x; comb[6][lane] = accs.y;
    comb[7][lane] = accs.z; comb[8][lane] = accs.w;
    comb[9][lane] = acct.x; comb[10][lane] = acct.y;
    comb[11][lane] = acct.z; comb[12][lane] = acct.w;
  }
  __syncthreads();
  if (half == 1) return;

  l += comb[0][lane];
  accf.x += comb[1][lane]; accf.y += comb[2][lane];
  accf.z += comb[3][lane]; accf.w += comb[4][lane];
  accs.x += comb[5][lane]; accs.y += comb[6][lane];
  accs.z += comb[7][lane]; accs.w += comb[8][lane];
  acct.x += comb[9][lane]; acct.y += comb[10][lane];
  acct.z += comb[11][lane]; acct.w += comb[12][lane];

  float invl = (l > 0.f) ? 1.f / l : 0.f;

  uint2 res2 = *reinterpret_cast<const uint2*>(resval + (size_t)n * 256 + fb);
  float4 of = make_float4(fmaxf(fmaf(accf.x, invl, bflo(res2.x)), 0.f),
                          fmaxf(fmaf(accf.y, invl, bfhi(res2.x)), 0.f),
                          fmaxf(fmaf(accf.z, invl, bflo(res2.y)), 0.f),
                          fmaxf(fmaf(accf.w, invl, bfhi(res2.y)), 0.f));
  float4 os = make_float4(accs.x * invl, accs.y * invl, accs.z * invl, accs.w * invl);
  float4 ot = make_float4(acct.x * invl, acct.y * invl, acct.z * invl, acct.w * invl);
#pragma unroll
  for (int msk = 8; msk <= 32; msk <<= 1) {
    of.x += __shfl_xor(of.x, msk); of.y += __shfl_xor(of.y, msk);
    of.z += __shfl_xor(of.z, msk); of.w += __shfl_xor(of.w, msk);
    os.x += __shfl_xor(os.x, msk); os.y += __shfl_xor(os.y, msk);
    os.z += __shfl_xor(os.z, msk); os.w += __shfl_xor(os.w, msk);
    ot.x += __shfl_xor(ot.x, msk); ot.y += __shfl_xor(ot.y, msk);
    ot.z += __shfl_xor(ot.z, msk); ot.w += __shfl_xor(ot.w, msk);
  }
  if (lane < 8) {
    float4 sln = *reinterpret_cast<const float4*>(sloc + (size_t)n * 32 + db);
    float4 tpn = *reinterpret_cast<const float4*>(topo + (size_t)n * 32 + db);
    float4 o0 = make_float4(of.x * 0.125f, of.y * 0.125f, of.z * 0.125f, of.w * 0.125f);
    float4 o1 = make_float4(fmaf(os.x, 0.125f, sln.x), fmaf(os.y, 0.125f, sln.y),
                            fmaf(os.z, 0.125f, sln.z), fmaf(os.w, 0.125f, sln.w));
    float4 o2 = make_float4(fmaf(ot.x, 0.125f, tpn.x), fmaf(ot.y, 0.125f, tpn.y),
                            fmaf(ot.z, 0.125f, tpn.z), fmaf(ot.w, 0.125f, tpn.w));
    *reinterpret_cast<float4*>(out + (size_t)n * 32 + db) = o0;
    *reinterpret_cast<float4*>(out + (size_t)N * 32 + (size_t)n * 32 + db) = o1;
    *reinterpret_cast<float4*>(out + (size_t)2 * N * 32 + (size_t)n * 32 + db) = o2;
  }
}

extern "C" void kernel_launch(void* const* d_in, const int* in_sizes, int n_in,
                              void* d_out, int out_size, void* d_ws, size_t ws_size,
                              hipStream_t stream) {
  const float* feat = (const float*)d_in[0];
  const float* sloc = (const float*)d_in[1];
  const float* topo = (const float*)d_in[2];
  const int* src = (const int*)d_in[3];
  const int* dst = (const int*)d_in[4];
  const int* e_feat = (const int*)d_in[5];
  const float* W_proj0 = (const float*)d_in[6];
  const float* W_proj1 = (const float*)d_in[7];
  const float* W_prob = (const float*)d_in[8];
  const float* W_res0 = (const float*)d_in[9];
  const float* W_res1 = (const float*)d_in[10];
  const float* etype_attn = (const float*)d_in[11];
  int E = in_sizes[3];
  int N = in_sizes[1] / 32;
  float* out = (float*)d_out;

  char* ws = (char*)d_ws;
  size_t off = 0;
  auto alloc = [&](size_t bytes) -> char* {
    char* p = ws + off;
    off += (bytes + 255) & ~(size_t)255;
    return p;
  };
  // contiguous zero-init group: deg | cursor | col_ss | gctr
  int* deg = (int*)alloc((size_t)N * 4);
  int* cursor = (int*)alloc((size_t)N * 4);
  float* col_ss = (float*)alloc(256 * 4);
  int* gctr = (int*)alloc(256);
  size_t zeroBytes = ((char*)gctr + 256) - (char*)deg;
  int* startArr = (int*)alloc(((size_t)N + 1) * 4);
  int* bsum = (int*)alloc(128 * 4);
  int2* csr = (int2*)alloc((size_t)E * 8);
  unsigned short* A_bf = (unsigned short*)alloc((size_t)N * 256 * 2);
  unsigned short* feat_bf = (unsigned short*)alloc((size_t)N * 256 * 2);
  unsigned short* slt = (unsigned short*)alloc((size_t)N * 64 * 2);
  unsigned short* sltn = (unsigned short*)alloc((size_t)N * 64 * 2);
  unsigned short* resval = (unsigned short*)alloc((size_t)N * 256 * 2);
  unsigned short* ft_attn = (unsigned short*)alloc((size_t)N * 256 * 2);
  unsigned short* BTw = (unsigned short*)alloc((size_t)2 * 512 * 256 * 2);

  hipMemsetAsync(deg, 0, zeroBytes, stream);

  int aBlocks = (N + 7) / 8;
  int nodeBlocks = (N + 7) / 8;
  int degBlocks = (E + 255) / 256;
  prep<<<64 + aBlocks + nodeBlocks + degBlocks, 256, 0, stream>>>(
      W_proj0, W_res0, W_proj1, W_res1, BTw, feat, A_bf, sloc, topo, slt, sltn,
      dst, deg, N, E);

  int g0t = (HN0 + BM - 1) / BM;
  int g1t = (N - HN0 + BM - 1) / BM;
  int R = g0t + g1t;
  int Gpad = ((R + 7) / 8) * 32;
  int nb = (N + 255) / 256;
  gemm_scan<<<Gpad + nb, 256, 0, stream>>>(A_bf, BTw, feat_bf, resval,
                                           deg, startArr, bsum, gctr, Gpad, R, N);

  int nAttn = (N + 15) / 16;
  int fillBlocks = (E + 63) / 64;
  attn_fill<<<nAttn + fillBlocks, 256, 0, stream>>>(
      feat_bf, W_prob, ft_attn, col_ss, src, dst, e_feat, etype_attn, sltn,
      startArr, bsum, cursor, csr, nAttn, N, E);

  edge_aggregate<<<N, 128, 0, stream>>>(feat_bf, resval, ft_attn, col_ss,
                                        slt, sloc, topo, startArr, bsum,
                                        deg, csr, out, N);
}

// Round 16
// 157.840 us; speedup vs baseline: 1.0193x; 1.0193x over previous
//
#include <hip/hip_runtime.h>
#include <math.h>

#define HN0 1373
#define BM 128
#define BN 128
#define BK 32
#define LDT 40  // GEMM LDS row stride in bf16 elems (80B = 5 x 16B units)

typedef __attribute__((ext_vector_type(8))) short short8;
typedef __attribute__((ext_vector_type(4))) float f32x4;

__device__ inline unsigned short f2bf(float f) {
  unsigned int u = __float_as_uint(f);
  unsigned int r = (u + 0x7FFFu + ((u >> 16) & 1u)) >> 16;
  return (unsigned short)r;
}
__device__ inline float bflo(unsigned int u) { return __uint_as_float(u << 16); }
__device__ inline float bfhi(unsigned int u) { return __uint_as_float(u & 0xFFFF0000u); }

__device__ inline uint4 pack8bf(float4 a, float4 b) {
  uint4 o;
  o.x = (unsigned)f2bf(a.x) | ((unsigned)f2bf(a.y) << 16);
  o.y = (unsigned)f2bf(a.z) | ((unsigned)f2bf(a.w) << 16);
  o.z = (unsigned)f2bf(b.x) | ((unsigned)f2bf(b.y) << 16);
  o.w = (unsigned)f2bf(b.z) | ((unsigned)f2bf(b.w) << 16);
  return o;
}

// ---- fused prep: W transpose | A->bf16 | node norms | deg hist --------------
__global__ __launch_bounds__(256) void prep(
    const float* __restrict__ Wp0, const float* __restrict__ Wr0,
    const float* __restrict__ Wp1, const float* __restrict__ Wr1,
    unsigned short* __restrict__ BTw,
    const float* __restrict__ A, unsigned short* __restrict__ A_bf,
    const float* __restrict__ sloc, const float* __restrict__ topo,
    unsigned short* __restrict__ slt, unsigned short* __restrict__ sltn,
    const int* __restrict__ dst, int* __restrict__ deg, int N, int E) {
  __shared__ float T[64][72];
  int b = blockIdx.x;
  int tid = threadIdx.x;
  int aBlocks = (N + 7) / 8;
  int nodeBlocks = (N + 7) / 8;
  if (b < 64) {
    int mat = b >> 4;
    int t16 = b & 15;
    int kT = (t16 & 3) * 64;
    int nT = (t16 >> 2) * 64;
    const float* W = (mat == 0) ? Wp0 : (mat == 1) ? Wr0 : (mat == 2) ? Wp1 : Wr1;
    int g = mat >> 1;
    int nbase = (mat & 1) * 256;
    int r = tid >> 2;
    int cb = (tid & 3) * 16;
    const float* srcp = W + (size_t)(kT + r) * 256 + nT + cb;
#pragma unroll
    for (int q = 0; q < 4; ++q) {
      float4 v = *reinterpret_cast<const float4*>(srcp + q * 4);
      T[cb + q * 4 + 0][r] = v.x;
      T[cb + q * 4 + 1][r] = v.y;
      T[cb + q * 4 + 2][r] = v.z;
      T[cb + q * 4 + 3][r] = v.w;
    }
    __syncthreads();
    int nl = tid >> 2;
    int kb = (tid & 3) * 16;
    unsigned int pk[8];
#pragma unroll
    for (int q = 0; q < 8; ++q) {
      unsigned short lo = f2bf(T[nl][kb + q * 2]);
      unsigned short hi = f2bf(T[nl][kb + q * 2 + 1]);
      pk[q] = (unsigned)lo | ((unsigned)hi << 16);
    }
    unsigned short* dstp = BTw + (size_t)g * 512 * 256 + (size_t)(nbase + nT + nl) * 256 + kT + kb;
    *reinterpret_cast<uint4*>(dstp) = make_uint4(pk[0], pk[1], pk[2], pk[3]);
    *reinterpret_cast<uint4*>(dstp + 8) = make_uint4(pk[4], pk[5], pk[6], pk[7]);
  } else if (b < 64 + aBlocks) {
    // A (fp32) -> A_bf (bf16), 8 rows per block
    int row = (b - 64) * 8 + (tid >> 5);
    if (row >= N) return;
    int cb = (tid & 31) * 8;
    const float* ap = A + (size_t)row * 256 + cb;
    float4 v0 = *reinterpret_cast<const float4*>(ap);
    float4 v1 = *reinterpret_cast<const float4*>(ap + 4);
    *reinterpret_cast<uint4*>(A_bf + (size_t)row * 256 + cb) = pack8bf(v0, v1);
  } else if (b < 64 + aBlocks + nodeBlocks) {
    int node = (b - 64 - aBlocks) * 8 + (tid >> 5);
    int d = tid & 31;
    if (node >= N) return;
    float s = sloc[(size_t)node * 32 + d];
    float t = topo[(size_t)node * 32 + d];
    float ss = s * s, tt = t * t;
#pragma unroll
    for (int m = 16; m >= 1; m >>= 1) {
      ss += __shfl_xor(ss, m);
      tt += __shfl_xor(tt, m);
    }
    float is = 1.f / fmaxf(sqrtf(ss), 1e-12f);
    float it = 1.f / fmaxf(sqrtf(tt), 1e-12f);
    slt[(size_t)node * 64 + d] = f2bf(s);
    slt[(size_t)node * 64 + 32 + d] = f2bf(t);
    sltn[(size_t)node * 64 + d] = f2bf(s * is);
    sltn[(size_t)node * 64 + 32 + d] = f2bf(t * it);
  } else {
    int e = (b - 64 - aBlocks - nodeBlocks) * 256 + tid;
    if (e < E) atomicAdd(&deg[dst[e]], 1);
  }
}

// ---- K2: MFMA GEMM (bf16 A, XCD-swizzled) + decoupled CSR scan --------------
__global__ __launch_bounds__(256) void gemm_scan(
    const unsigned short* __restrict__ A_bf, const unsigned short* __restrict__ BTw,
    unsigned short* __restrict__ feat_bf, unsigned short* __restrict__ resval,
    const int* __restrict__ deg, int* __restrict__ start, int* __restrict__ bsum,
    int* __restrict__ gctr, int Gpad, int R, int N) {
  int b = blockIdx.x;
  int tid = threadIdx.x;
  if (b >= Gpad) {
    __shared__ int buf[256];
    int b2 = b - Gpad;
    int gid = b2 * 256 + tid;
    int v = (gid < N) ? deg[gid] : 0;
    buf[tid] = v;
    __syncthreads();
    for (int off = 1; off < 256; off <<= 1) {
      int t = (tid >= off) ? buf[tid - off] : 0;
      __syncthreads();
      buf[tid] += t;
      __syncthreads();
    }
    if (gid < N) start[gid] = buf[tid] - v;
    if (tid == 255) bsum[b2] = atomicAdd(gctr, buf[255]);
    return;
  }
  int r8 = b & 7;
  int c = (b >> 3) & 3;
  int bx = (b >> 5) * 8 + r8;
  if (bx >= R) return;
  int colBase = c * BN;

  __shared__ __align__(16) unsigned short As[BM * LDT];
  __shared__ __align__(16) unsigned short Bs[BN * LDT];
  int lane = tid & 63;
  int w = tid >> 6;
  int wr = w >> 1, wc = w & 1;

  int g0t = (HN0 + BM - 1) / BM;
  bool g1 = bx >= g0t;
  int rowBase = g1 ? HN0 + (bx - g0t) * BM : bx * BM;
  int rowEnd = g1 ? N : HN0;
  const unsigned short* BT = BTw + (g1 ? (size_t)512 * 256 : 0);

  int r0 = tid >> 2;
  int kp = (tid & 3) << 3;
  int ar1 = min(rowBase + r0, rowEnd - 1);
  int ar2 = min(rowBase + r0 + 64, rowEnd - 1);
  const unsigned short* aP1 = A_bf + (size_t)ar1 * 256 + kp;
  const unsigned short* aP2 = A_bf + (size_t)ar2 * 256 + kp;
  const unsigned short* bP1 = BT + (size_t)(colBase + r0) * 256 + kp;
  const unsigned short* bP2 = bP1 + (size_t)64 * 256;
  int wo1 = r0 * LDT + kp;
  int wo2 = (r0 + 64) * LDT + kp;

  int q = lane >> 4;
  int fr = lane & 15;
  int aOff = (wr * 64 + fr) * LDT + q * 8;
  int bOff = (wc * 64 + fr) * LDT + q * 8;

  f32x4 acc[4][4] = {};

  uint4 ra1 = *reinterpret_cast<const uint4*>(aP1);
  uint4 ra2 = *reinterpret_cast<const uint4*>(aP2);
  uint4 rb1 = *reinterpret_cast<const uint4*>(bP1);
  uint4 rb2 = *reinterpret_cast<const uint4*>(bP2);

  for (int t = 0; t < 8; ++t) {
    *reinterpret_cast<uint4*>(&As[wo1]) = ra1;
    *reinterpret_cast<uint4*>(&As[wo2]) = ra2;
    *reinterpret_cast<uint4*>(&Bs[wo1]) = rb1;
    *reinterpret_cast<uint4*>(&Bs[wo2]) = rb2;
    __syncthreads();
    if (t < 7) {
      int ko = (t + 1) * BK;
      ra1 = *reinterpret_cast<const uint4*>(aP1 + ko);
      ra2 = *reinterpret_cast<const uint4*>(aP2 + ko);
      rb1 = *reinterpret_cast<const uint4*>(bP1 + ko);
      rb2 = *reinterpret_cast<const uint4*>(bP2 + ko);
    }
    short8 af[4], bf4[4];
#pragma unroll
    for (int i = 0; i < 4; ++i) {
      af[i] = *reinterpret_cast<const short8*>(&As[aOff + i * 16 * LDT]);
      bf4[i] = *reinterpret_cast<const short8*>(&Bs[bOff + i * 16 * LDT]);
    }
#pragma unroll
    for (int i = 0; i < 4; ++i)
#pragma unroll
      for (int j = 0; j < 4; ++j)
        acc[i][j] = __builtin_amdgcn_mfma_f32_16x16x32_bf16(af[i], bf4[j], acc[i][j], 0, 0, 0);
    __syncthreads();
  }

  unsigned short* outp = (colBase < 256) ? feat_bf : resval;
  int cOff = colBase & 255;
#pragma unroll
  for (int i = 0; i < 4; ++i) {
    int rb = rowBase + wr * 64 + i * 16 + q * 4;
#pragma unroll
    for (int j = 0; j < 4; ++j) {
      int col = cOff + wc * 64 + j * 16 + fr;
      f32x4 v = acc[i][j];
#pragma unroll
      for (int rr = 0; rr < 4; ++rr) {
        int r = rb + rr;
        if (r < rowEnd) outp[(size_t)r * 256 + col] = f2bf(v[rr]);
      }
    }
  }
}

// ---- K3: attn_probs (blocks < nAttn, conflict-free LDS) ∪ fill_sim ----------
#define HSTR 36  // head stride in fsL floats: 4h+f banks, 16B aligned
__global__ __launch_bounds__(256) void attn_fill(
    const unsigned short* __restrict__ feat_bf, const float* __restrict__ W_prob,
    unsigned short* __restrict__ ft_attn, float* __restrict__ col_ss,
    const int* __restrict__ src, const int* __restrict__ dst,
    const int* __restrict__ e_feat, const float* __restrict__ etype_attn,
    const unsigned short* __restrict__ sltn,
    const int* __restrict__ start, const int* __restrict__ bsum,
    int* __restrict__ cursor, int2* __restrict__ csr,
    int nAttn, int N, int E) {
  int tid = threadIdx.x;
  if ((int)blockIdx.x >= nAttn) {
    int j = tid & 3;
    int e = ((int)blockIdx.x - nAttn) * 64 + (tid >> 2);
    if (e >= E) return;
    int s = src[e], d = dst[e];
    const unsigned short* ps = sltn + (size_t)s * 64 + j * 16;
    const unsigned short* pd = sltn + (size_t)d * 64 + j * 16;
    uint4 a0 = *reinterpret_cast<const uint4*>(ps);
    uint4 a1 = *reinterpret_cast<const uint4*>(ps + 8);
    uint4 b0 = *reinterpret_cast<const uint4*>(pd);
    uint4 b1 = *reinterpret_cast<const uint4*>(pd + 8);
    float u = bflo(a0.x) * bflo(b0.x) + bfhi(a0.x) * bfhi(b0.x) +
              bflo(a0.y) * bflo(b0.y) + bfhi(a0.y) * bfhi(b0.y) +
              bflo(a0.z) * bflo(b0.z) + bfhi(a0.z) * bfhi(b0.z) +
              bflo(a0.w) * bflo(b0.w) + bfhi(a0.w) * bfhi(b0.w) +
              bflo(a1.x) * bflo(b1.x) + bfhi(a1.x) * bfhi(b1.x) +
              bflo(a1.y) * bflo(b1.y) + bfhi(a1.y) * bfhi(b1.y) +
              bflo(a1.z) * bflo(b1.z) + bfhi(a1.z) * bfhi(b1.z) +
              bflo(a1.w) * bflo(b1.w) + bfhi(a1.w) * bfhi(b1.w);
    u *= (j < 2) ? 0.4f : 0.6f;
    u += __shfl_xor(u, 1);
    u += __shfl_xor(u, 2);
    if (j == 0) {
      float sim = fmaf(u, 0.5f, 0.5f);
      float wv = sim * etype_attn[e_feat[e]];
      int pos = start[d] + bsum[d >> 8] + atomicAdd(&cursor[d], 1);
      csr[pos] = make_int2(s, __float_as_int(wv));
    }
    return;
  }
  __shared__ float fsL[16 * 8 * HSTR];  // [node][head*HSTR + f]
  int h = tid >> 5, g = tid & 31;
  float wreg[32];
#pragma unroll
  for (int f = 0; f < 32; ++f) wreg[f] = W_prob[h * 1024 + f * 32 + g];
  int nodeBase = blockIdx.x * 16;
  {
    int nloc = tid >> 6;
    int cb = (tid & 63) * 4;
    int hh = cb >> 5, ff = cb & 31;
#pragma unroll
    for (int it = 0; it < 4; ++it) {
      int nl = it * 4 + nloc;
      int n = nodeBase + nl;
      float4 v = make_float4(0.f, 0.f, 0.f, 0.f);
      if (n < N) {
        uint2 p = *reinterpret_cast<const uint2*>(feat_bf + (size_t)n * 256 + cb);
        v = make_float4(bflo(p.x), bfhi(p.x), bflo(p.y), bfhi(p.y));
      }
      *reinterpret_cast<float4*>(&fsL[nl * 8 * HSTR + hh * HSTR + ff]) = v;
    }
  }
  __syncthreads();
  {
    float ssp = 0.f;
#pragma unroll
    for (int nl = 0; nl < 16; ++nl) {
      float v = fsL[nl * 8 * HSTR + h * HSTR + g];
      ssp += v * v;
    }
    atomicAdd(&col_ss[tid], ssp);
  }
  for (int i = 0; i < 16; ++i) {
    int n = nodeBase + i;
    if (n >= N) break;
    const float* frp = &fsL[i * 8 * HSTR + h * HSTR];
    float t0 = 0.f, t1 = 0.f, t2 = 0.f, t3 = 0.f;
#pragma unroll
    for (int f = 0; f < 8; ++f) {
      t0 = fmaf(frp[f * 4 + 0], wreg[f * 4 + 0], t0);
      t1 = fmaf(frp[f * 4 + 1], wreg[f * 4 + 1], t1);
      t2 = fmaf(frp[f * 4 + 2], wreg[f * 4 + 2], t2);
      t3 = fmaf(frp[f * 4 + 3], wreg[f * 4 + 3], t3);
    }
    float t = (t0 + t1) + (t2 + t3);
    float e2 = __expf(2.f * t);
    t = 1.f - 2.f * __builtin_amdgcn_rcpf(e2 + 1.f);  // tanh(t)
    float ex = __expf(t);                             // bounded: safe
    float sm = ex;
#pragma unroll
    for (int s = 16; s >= 1; s >>= 1) sm += __shfl_xor(sm, s);
    ft_attn[(size_t)n * 256 + tid] = f2bf(ex * __builtin_amdgcn_rcpf(sm));
  }
}

// --------------- main: one wave/node, depth-3 pipeline (converged floor) -----
#define LOADIDX(K, V, W)                                                       \
  do {                                                                         \
    int2 c_ = csr[s0 + (K)];                                                   \
    V = c_.x;                                                                  \
    W = __int_as_float(c_.y);                                                  \
  } while (0)

#define GATHER(V, FP, SL, TP)                                                  \
  do {                                                                         \
    FP = *reinterpret_cast<const uint2*>(feat_bf + (size_t)(V) * 256 + fb);    \
    const unsigned short* sp_ = slt + (size_t)(V) * 64 + db;                   \
    SL = *reinterpret_cast<const uint2*>(sp_);                                 \
    TP = *reinterpret_cast<const uint2*>(sp_ + 32);                            \
  } while (0)

#define CONSUME(W, FP, SL, TP)                                                 \
  do {                                                                         \
    float fs0 = bflo(FP.x), fs1 = bfhi(FP.x);                                  \
    float fs2 = bflo(FP.y), fs3 = bfhi(FP.y);                                  \
    float pa = ai4.x * fs0 + ai4.y * fs1 + ai4.z * fs2 + ai4.w * fs3;          \
    pa += __shfl_xor(pa, 1);                                                   \
    pa += __shfl_xor(pa, 2);                                                   \
    pa += __shfl_xor(pa, 4);                                                   \
    float p = __expf(pa * (W));                                                \
    l += p;                                                                    \
    accf.x = fmaf(p, fs0, accf.x); accf.y = fmaf(p, fs1, accf.y);              \
    accf.z = fmaf(p, fs2, accf.z); accf.w = fmaf(p, fs3, accf.w);              \
    accs.x = fmaf(p, bflo(SL.x), accs.x); accs.y = fmaf(p, bfhi(SL.x), accs.y);\
    accs.z = fmaf(p, bflo(SL.y), accs.z); accs.w = fmaf(p, bfhi(SL.y), accs.w);\
    acct.x = fmaf(p, bflo(TP.x), acct.x); acct.y = fmaf(p, bfhi(TP.x), acct.y);\
    acct.z = fmaf(p, bflo(TP.y), acct.z); acct.w = fmaf(p, bfhi(TP.y), acct.w);\
  } while (0)

__global__ __launch_bounds__(128) void edge_aggregate(
    const unsigned short* __restrict__ feat_bf, const unsigned short* __restrict__ resval,
    const unsigned short* __restrict__ ft_attn, const float* __restrict__ col_ss,
    const unsigned short* __restrict__ slt,
    const float* __restrict__ sloc, const float* __restrict__ topo,
    const int* __restrict__ start, const int* __restrict__ bsum,
    const int* __restrict__ deg, const int2* __restrict__ csr,
    float* __restrict__ out, int N) {
  int wave = threadIdx.x >> 6;
  int n = blockIdx.x * 2 + wave;
  if (n >= N) return;
  int lane = threadIdx.x & 63;
  int j = lane & 7;
  int fb = (lane >> 3) * 32 + j * 4;
  int db = j * 4;

  uint2 at2 = *reinterpret_cast<const uint2*>(ft_attn + (size_t)n * 256 + fb);
  float4 cs4 = *reinterpret_cast<const float4*>(col_ss + fb);
  float4 icn4 = make_float4(1.f / fmaxf(sqrtf(cs4.x), 1e-12f),
                            1.f / fmaxf(sqrtf(cs4.y), 1e-12f),
                            1.f / fmaxf(sqrtf(cs4.z), 1e-12f),
                            1.f / fmaxf(sqrtf(cs4.w), 1e-12f));
  float4 ai4 = make_float4(bflo(at2.x) * icn4.x, bfhi(at2.x) * icn4.y,
                           bflo(at2.y) * icn4.z, bfhi(at2.y) * icn4.w);
  float l = 0.f;
  float4 accf = make_float4(0.f, 0.f, 0.f, 0.f);
  float4 accs = make_float4(0.f, 0.f, 0.f, 0.f);
  float4 acct = make_float4(0.f, 0.f, 0.f, 0.f);
  int s0 = start[n] + bsum[n >> 8];
  int dg = deg[n];

  int vA = 0, vB = 0, vC = 0;
  float wA = 0.f, wB = 0.f, wC = 0.f;
  uint2 fpA = make_uint2(0u, 0u), fpB = make_uint2(0u, 0u), fpC = make_uint2(0u, 0u);
  uint2 slA = make_uint2(0u, 0u), slB = make_uint2(0u, 0u), slC = make_uint2(0u, 0u);
  uint2 tpA = make_uint2(0u, 0u), tpB = make_uint2(0u, 0u), tpC = make_uint2(0u, 0u);
  if (dg > 0) { LOADIDX(0, vA, wA); GATHER(vA, fpA, slA, tpA); }
  if (dg > 1) { LOADIDX(1, vB, wB); GATHER(vB, fpB, slB, tpB); }
  if (dg > 2) { LOADIDX(2, vC, wC); GATHER(vC, fpC, slC, tpC); }
  int i = 0;
  for (; i + 2 < dg; i += 3) {
    CONSUME(wA, fpA, slA, tpA);
    if (i + 3 < dg) { LOADIDX(i + 3, vA, wA); GATHER(vA, fpA, slA, tpA); }
    CONSUME(wB, fpB, slB, tpB);
    if (i + 4 < dg) { LOADIDX(i + 4, vB, wB); GATHER(vB, fpB, slB, tpB); }
    CONSUME(wC, fpC, slC, tpC);
    if (i + 5 < dg) { LOADIDX(i + 5, vC, wC); GATHER(vC, fpC, slC, tpC); }
  }
  if (i < dg) CONSUME(wA, fpA, slA, tpA);
  if (i + 1 < dg) CONSUME(wB, fpB, slB, tpB);

  float invl = (l > 0.f) ? 1.f / l : 0.f;

  uint2 res2 = *reinterpret_cast<const uint2*>(resval + (size_t)n * 256 + fb);
  float4 of = make_float4(fmaxf(fmaf(accf.x, invl, bflo(res2.x)), 0.f),
                          fmaxf(fmaf(accf.y, invl, bfhi(res2.x)), 0.f),
                          fmaxf(fmaf(accf.z, invl, bflo(res2.y)), 0.f),
                          fmaxf(fmaf(accf.w, invl, bfhi(res2.y)), 0.f));
  float4 os = make_float4(accs.x * invl, accs.y * invl, accs.z * invl, accs.w * invl);
  float4 ot = make_float4(acct.x * invl, acct.y * invl, acct.z * invl, acct.w * invl);
#pragma unroll
  for (int msk = 8; msk <= 32; msk <<= 1) {
    of.x += __shfl_xor(of.x, msk); of.y += __shfl_xor(of.y, msk);
    of.z += __shfl_xor(of.z, msk); of.w += __shfl_xor(of.w, msk);
    os.x += __shfl_xor(os.x, msk); os.y += __shfl_xor(os.y, msk);
    os.z += __shfl_xor(os.z, msk); os.w += __shfl_xor(os.w, msk);
    ot.x += __shfl_xor(ot.x, msk); ot.y += __shfl_xor(ot.y, msk);
    ot.z += __shfl_xor(ot.z, msk); ot.w += __shfl_xor(ot.w, msk);
  }
  if (lane < 8) {
    float4 sln = *reinterpret_cast<const float4*>(sloc + (size_t)n * 32 + db);
    float4 tpn = *reinterpret_cast<const float4*>(topo + (size_t)n * 32 + db);
    float4 o0 = make_float4(of.x * 0.125f, of.y * 0.125f, of.z * 0.125f, of.w * 0.125f);
    float4 o1 = make_float4(fmaf(os.x, 0.125f, sln.x), fmaf(os.y, 0.125f, sln.y),
                            fmaf(os.z, 0.125f, sln.z), fmaf(os.w, 0.125f, sln.w));
    float4 o2 = make_float4(fmaf(ot.x, 0.125f, tpn.x), fmaf(ot.y, 0.125f, tpn.y),
                            fmaf(ot.z, 0.125f, tpn.z), fmaf(ot.w, 0.125f, tpn.w));
    *reinterpret_cast<float4*>(out + (size_t)n * 32 + db) = o0;
    *reinterpret_cast<float4*>(out + (size_t)N * 32 + (size_t)n * 32 + db) = o1;
    *reinterpret_cast<float4*>(out + (size_t)2 * N * 32 + (size_t)n * 32 + db) = o2;
  }
}

extern "C" void kernel_launch(void* const* d_in, const int* in_sizes, int n_in,
                              void* d_out, int out_size, void* d_ws, size_t ws_size,
                              hipStream_t stream) {
  const float* feat = (const float*)d_in[0];
  const float* sloc = (const float*)d_in[1];
  const float* topo = (const float*)d_in[2];
  const int* src = (const int*)d_in[3];
  const int* dst = (const int*)d_in[4];
  const int* e_feat = (const int*)d_in[5];
  const float* W_proj0 = (const float*)d_in[6];
  const float* W_proj1 = (const float*)d_in[7];
  const float* W_prob = (const float*)d_in[8];
  const float* W_res0 = (const float*)d_in[9];
  const float* W_res1 = (const float*)d_in[10];
  const float* etype_attn = (const float*)d_in[11];
  int E = in_sizes[3];
  int N = in_sizes[1] / 32;
  float* out = (float*)d_out;

  char* ws = (char*)d_ws;
  size_t off = 0;
  auto alloc = [&](size_t bytes) -> char* {
    char* p = ws + off;
    off += (bytes + 255) & ~(size_t)255;
    return p;
  };
  // contiguous zero-init group: deg | cursor | col_ss | gctr
  int* deg = (int*)alloc((size_t)N * 4);
  int* cursor = (int*)alloc((size_t)N * 4);
  float* col_ss = (float*)alloc(256 * 4);
  int* gctr = (int*)alloc(256);
  size_t zeroBytes = ((char*)gctr + 256) - (char*)deg;
  int* startArr = (int*)alloc(((size_t)N + 1) * 4);
  int* bsum = (int*)alloc(128 * 4);
  int2* csr = (int2*)alloc((size_t)E * 8);
  unsigned short* A_bf = (unsigned short*)alloc((size_t)N * 256 * 2);
  unsigned short* feat_bf = (unsigned short*)alloc((size_t)N * 256 * 2);
  unsigned short* slt = (unsigned short*)alloc((size_t)N * 64 * 2);
  unsigned short* sltn = (unsigned short*)alloc((size_t)N * 64 * 2);
  unsigned short* resval = (unsigned short*)alloc((size_t)N * 256 * 2);
  unsigned short* ft_attn = (unsigned short*)alloc((size_t)N * 256 * 2);
  unsigned short* BTw = (unsigned short*)alloc((size_t)2 * 512 * 256 * 2);

  hipMemsetAsync(deg, 0, zeroBytes, stream);

  int aBlocks = (N + 7) / 8;
  int nodeBlocks = (N + 7) / 8;
  int degBlocks = (E + 255) / 256;
  prep<<<64 + aBlocks + nodeBlocks + degBlocks, 256, 0, stream>>>(
      W_proj0, W_res0, W_proj1, W_res1, BTw, feat, A_bf, sloc, topo, slt, sltn,
      dst, deg, N, E);

  int g0t = (HN0 + BM - 1) / BM;
  int g1t = (N - HN0 + BM - 1) / BM;
  int R = g0t + g1t;
  int Gpad = ((R + 7) / 8) * 32;
  int nb = (N + 255) / 256;
  gemm_scan<<<Gpad + nb, 256, 0, stream>>>(A_bf, BTw, feat_bf, resval,
                                           deg, startArr, bsum, gctr, Gpad, R, N);

  int nAttn = (N + 15) / 16;
  int fillBlocks = (E + 63) / 64;
  attn_fill<<<nAttn + fillBlocks, 256, 0, stream>>>(
      feat_bf, W_prob, ft_attn, col_ss, src, dst, e_feat, etype_attn, sltn,
      startArr, bsum, cursor, csr, nAttn, N, E);

  edge_aggregate<<<(N + 1) / 2, 128, 0, stream>>>(feat_bf, resval, ft_attn, col_ss,
                                                  slt, sloc, topo, startArr, bsum,
                                                  deg, csr, out, N);
}